// Round 1
// baseline (2528.533 us; speedup 1.0000x reference)
//
#include <hip/hip_runtime.h>
#include <hip/hip_bf16.h>

#define NCN 300000
#define NAN_ 100000
#define DIM 128
#define NE 2000000
#define NL 1000000

typedef __attribute__((ext_vector_type(8))) short bf16x8;
typedef __attribute__((ext_vector_type(4))) float f32x4;
typedef __attribute__((ext_vector_type(8))) unsigned short u16x8;
typedef __attribute__((ext_vector_type(4))) unsigned short u16x4;

static __device__ __forceinline__ unsigned short f2bf(float x){
  union { float f; unsigned u; } v; v.f = x;
  unsigned r = (v.u + 0x7FFFu + ((v.u >> 16) & 1u)) >> 16;
  return (unsigned short)r;
}

// ---------------- CSR build ----------------
__global__ void k_count(const int* __restrict__ src, const int* __restrict__ dst,
                        int* dega, int* degc){
  int e = blockIdx.x * blockDim.x + threadIdx.x;
  if (e < NE){
    atomicAdd(&dega[dst[e]], 1);
    atomicAdd(&degc[src[e]], 1);
  }
}

// per-4096-chunk exclusive scan (256 thr x 16 elems), block totals out
__global__ void k_scan1(const int* __restrict__ in, int* __restrict__ out,
                        int* __restrict__ bsum, int n){
  int t = threadIdx.x;
  int base = blockIdx.x * 4096 + t * 16;
  int v[16];
  int tot = 0;
  #pragma unroll
  for (int i = 0; i < 16; i++){
    int x = (base + i < n) ? in[base + i] : 0;
    v[i] = tot; tot += x;
  }
  int lane = t & 63, w = t >> 6;
  int inc = tot;
  #pragma unroll
  for (int o = 1; o < 64; o <<= 1){ int u = __shfl_up(inc, o); if (lane >= o) inc += u; }
  __shared__ int ws[4];
  if (lane == 63) ws[w] = inc;
  __syncthreads();
  int woff = 0;
  for (int j = 0; j < w; j++) woff += ws[j];
  int ex = woff + inc - tot;
  #pragma unroll
  for (int i = 0; i < 16; i++) if (base + i < n) out[base + i] = ex + v[i];
  if (t == 255) bsum[blockIdx.x] = woff + inc;
}

// exclusive scan of block totals (nb <= 128), single block of 128
__global__ void k_scanb(int* bs, int nb){
  int t = threadIdx.x;
  int vv = (t < nb) ? bs[t] : 0;
  int lane = t & 63, w = t >> 6;
  int inc = vv;
  #pragma unroll
  for (int o = 1; o < 64; o <<= 1){ int u = __shfl_up(inc, o); if (lane >= o) inc += u; }
  __shared__ int ws[2];
  if (lane == 63) ws[w] = inc;
  __syncthreads();
  int off = (w == 1) ? ws[0] : 0;
  if (t < nb) bs[t] = off + inc - vv;
}

__global__ void k_scan3(int* __restrict__ rp, const int* __restrict__ bs, int n, int total){
  int idx = blockIdx.x * blockDim.x + threadIdx.x;
  if (idx < n) rp[idx] += bs[idx >> 12];
  if (idx == 0) rp[n] = total;
}

__global__ void k_scatter(const int* __restrict__ src, const int* __restrict__ dst,
                          const int* __restrict__ rpa, const int* __restrict__ rpc,
                          int* cura, int* curc, int* cola, int* colc){
  int e = blockIdx.x * blockDim.x + threadIdx.x;
  if (e < NE){
    int s = src[e], d = dst[e];
    int pa = rpa[d] + atomicAdd(&cura[d], 1);
    cola[pa] = s;
    int pc = rpc[s] + atomicAdd(&curc[s], 1);
    colc[pc] = d;
  }
}

// ---------------- pull-based mean aggregation: one wave per destination ----------------
__global__ void k_agg(const float* __restrict__ feat, const int* __restrict__ rp,
                      const int* __restrict__ col, float* __restrict__ outm, int ndst){
  int wid  = (blockIdx.x * blockDim.x + threadIdx.x) >> 6;
  int lane = threadIdx.x & 63;
  if (wid >= ndst) return;
  int beg = rp[wid], end = rp[wid + 1];
  float ax = 0.f, ay = 0.f;
  for (int j = beg; j < end; ++j){
    int s = col[j];
    const float2 v = *(const float2*)(feat + (size_t)s * DIM + lane * 2);
    ax += v.x; ay += v.y;
  }
  int d = end - beg;
  float inv = 1.0f / (float)(d > 1 ? d : 1);
  float2 r; r.x = ax * inv; r.y = ay * inv;
  *(float2*)(outm + (size_t)wid * DIM + lane * 2) = r;
}

// ---------------- bf16 MFMA GEMM: out[M x128] = A@WA (+ B@WB) + bias, optional relu ----
// WtA/WtB are bf16, TRANSPOSED [n][k]. In-place (out aliasing A or B) is safe:
// each block stages all its input rows into LDS before any global store.
__global__ __launch_bounds__(256) void k_gemm(
    const float* __restrict__ A, const unsigned short* __restrict__ WtA,
    const float* __restrict__ B, const unsigned short* __restrict__ WtB,
    const float* __restrict__ bias, float* out, int M, int doRelu)
{
  __shared__ unsigned short lA[128 * 128];   // 32 KB, xor-swizzled 16B chunks
  __shared__ unsigned short lW[128 * 128];   // 32 KB  (total exactly 64 KB)
  int t = threadIdx.x;
  int lane = t & 63, wv = t >> 6;
  int row0 = blockIdx.x * 128;
  int m = lane & 15, kq = lane >> 4;

  f32x4 acc[2][8];
  #pragma unroll
  for (int i = 0; i < 2; i++)
    #pragma unroll
    for (int j = 0; j < 8; j++) acc[i][j] = (f32x4){0.f, 0.f, 0.f, 0.f};

  const float* src = A;
  const unsigned short* wt = WtA;
  for (int pass = 0; pass < 2; ++pass){
    if (pass == 1){
      if (!B) break;
      src = B; wt = WtB;
      __syncthreads();
    }
    // stage activation tile fp32->bf16 (swizzle key = row&15 over 16B chunks)
    #pragma unroll
    for (int i = 0; i < 16; i++){
      int id = t + 256 * i;            // 0..4095 float4 units
      int r = id >> 5, p = id & 31;    // p = 8B piece (4 bf16)
      int gr = row0 + r;
      float4 vv;
      if (gr < M) vv = *(const float4*)(src + (size_t)gr * DIM + p * 4);
      else { vv.x = 0.f; vv.y = 0.f; vv.z = 0.f; vv.w = 0.f; }
      u16x4 h;
      h[0] = f2bf(vv.x); h[1] = f2bf(vv.y); h[2] = f2bf(vv.z); h[3] = f2bf(vv.w);
      int c = p >> 1, half = p & 1;
      int pp = ((c ^ (r & 15)) << 1) | half;
      *(u16x4*)&lA[r * 128 + pp * 4] = h;
    }
    // stage transposed weight (already bf16 [n][k]) swizzled
    #pragma unroll
    for (int i = 0; i < 8; i++){
      int id = t + 256 * i;            // 0..2047 16B chunks
      int n = id >> 4, cc = id & 15;
      u16x8 w = *(const u16x8*)(wt + n * 128 + cc * 8);
      int pc = cc ^ (n & 15);
      *(u16x8*)&lW[n * 128 + pc * 8] = w;
    }
    __syncthreads();
    #pragma unroll
    for (int kc = 0; kc < 4; kc++){
      int cA = kc * 4 + kq;            // logical 16B chunk = 8 k-elems
      int r0 = wv * 32 + m;
      int r1 = r0 + 16;
      bf16x8 a0 = *(const bf16x8*)&lA[r0 * 128 + (cA ^ m) * 8];
      bf16x8 a1 = *(const bf16x8*)&lA[r1 * 128 + (cA ^ m) * 8];
      #pragma unroll
      for (int ct = 0; ct < 8; ct++){
        int n = ct * 16 + m;
        bf16x8 bfrag = *(const bf16x8*)&lW[n * 128 + (cA ^ m) * 8];
        acc[0][ct] = __builtin_amdgcn_mfma_f32_16x16x32_bf16(a0, bfrag, acc[0][ct], 0, 0, 0);
        acc[1][ct] = __builtin_amdgcn_mfma_f32_16x16x32_bf16(a1, bfrag, acc[1][ct], 0, 0, 0);
      }
    }
  }
  // epilogue: D col = lane&15, row = (lane>>4)*4 + reg   [verified m89/m91]
  #pragma unroll
  for (int rt = 0; rt < 2; rt++){
    int rbase = row0 + wv * 32 + rt * 16 + kq * 4;
    #pragma unroll
    for (int ct = 0; ct < 8; ct++){
      int colv = ct * 16 + m;
      float bv = bias ? bias[colv] : 0.f;
      #pragma unroll
      for (int r = 0; r < 4; r++){
        int grow = rbase + r;
        if (grow < M){
          float vo = acc[rt][ct][r] + bv;
          if (doRelu) vo = fmaxf(vo, 0.f);
          out[(size_t)grow * DIM + colv] = vo;
        }
      }
    }
  }
}

// ---------------- weight transpose fp32 [k][n] -> bf16 [n][k], batched ----------------
struct WtArgs { const float* s[8]; };
__global__ void k_wtrans(WtArgs a, unsigned short* dstb){
  const float* W = a.s[blockIdx.x];
  unsigned short* Wt = dstb + blockIdx.x * 16384;
  int t = threadIdx.x;
  for (int i = 0; i < 64; i++){
    int id = t + 256 * i;
    int k = id >> 7, n = id & 127;
    Wt[n * 128 + k] = f2bf(W[id]);
  }
}

// ---------------- batch-norm column stats ----------------
__global__ void k_bnstats(const float* __restrict__ z, int M, float* gsum, float* gsq){
  int ch = threadIdx.x & 127, half = threadIdx.x >> 7;
  float s = 0.f, q = 0.f;
  for (int r = blockIdx.x * 2 + half; r < M; r += gridDim.x * 2){
    float v = z[(size_t)r * DIM + ch];
    s += v; q += v * v;
  }
  __shared__ float ls[256], lq[256];
  ls[threadIdx.x] = s; lq[threadIdx.x] = q;
  __syncthreads();
  if (half == 0){
    atomicAdd(&gsum[ch], ls[ch] + ls[ch + 128]);
    atomicAdd(&gsq[ch],  lq[ch] + lq[ch + 128]);
  }
}

// bn finalize + fold BN into decoder weight halves; bfull = b_dec1 + t_c@Wc + t_a@Wa
__global__ void k_bnprep(const float* sums,   // [sum_a, sq_a, sum_c, sq_c] x128
                         const float* gc, const float* bc,
                         const float* ga, const float* ba,
                         const float* Wd1, const float* bd1,
                         unsigned short* Wpt_c, unsigned short* Wpt_a, float* bfull){
  int n = threadIdx.x;   // 128 threads
  __shared__ float sc[128], tc[128], sa[128], ta[128];
  {
    float mu = sums[256 + n] / (float)NCN;
    float var = sums[384 + n] / (float)NCN - mu * mu;
    float s = gc[n] * rsqrtf(var + 1e-5f);
    sc[n] = s; tc[n] = bc[n] - mu * s;
  }
  {
    float mu = sums[0 + n] / (float)NAN_;
    float var = sums[128 + n] / (float)NAN_ - mu * mu;
    float s = ga[n] * rsqrtf(var + 1e-5f);
    sa[n] = s; ta[n] = ba[n] - mu * s;
  }
  __syncthreads();
  float accv = bd1[n];
  for (int k = 0; k < 128; k++){
    float w1 = Wd1[k * DIM + n];
    float w2 = Wd1[(128 + k) * DIM + n];
    Wpt_c[n * 128 + k] = f2bf(sc[k] * w1);
    Wpt_a[n * 128 + k] = f2bf(sa[k] * w2);
    accv += tc[k] * w1 + ta[k] * w2;
  }
  bfull[n] = accv;
}

// ---------------- decoder: one wave per label edge ----------------
__global__ void k_dec(const int* __restrict__ lc, const int* __restrict__ la,
                      const float* __restrict__ UC, const float* __restrict__ UA,
                      const float* __restrict__ bfull, const float* __restrict__ w2,
                      const float* __restrict__ b2, float* __restrict__ out, int Etot){
  int lane = threadIdx.x & 63;
  int wid  = (blockIdx.x * blockDim.x + threadIdx.x) >> 6;
  int nw   = (gridDim.x * blockDim.x) >> 6;
  float2 bb = *(const float2*)(bfull + lane * 2);
  float2 ww = *(const float2*)(w2 + lane * 2);
  float b2v = b2[0];
  for (int e = wid; e < Etot; e += nw){
    int ic = lc[e], ia = la[e];
    float2 uc = *(const float2*)(UC + (size_t)ic * DIM + lane * 2);
    float2 ua = *(const float2*)(UA + (size_t)ia * DIM + lane * 2);
    float x = fmaxf(uc.x + ua.x + bb.x, 0.f);
    float y = fmaxf(uc.y + ua.y + bb.y, 0.f);
    float d = x * ww.x + y * ww.y;
    #pragma unroll
    for (int o = 32; o; o >>= 1) d += __shfl_xor(d, o);
    if (lane == 0) out[e] = d + b2v;
  }
}

extern "C" void kernel_launch(void* const* d_in, const int* in_sizes, int n_in,
                              void* d_out, int out_size, void* d_ws, size_t ws_size,
                              hipStream_t stream){
  const float* x_c  = (const float*)d_in[0];
  const float* x_a  = (const float*)d_in[1];
  const int* e_src  = (const int*)d_in[2];
  const int* e_dst  = (const int*)d_in[3];
  const int* l_c    = (const int*)d_in[4];
  const int* l_a    = (const int*)d_in[5];
  const float* Wm1ca = (const float*)d_in[6];
  const float* Ws1a  = (const float*)d_in[7];
  const float* b1a   = (const float*)d_in[8];
  const float* Wm1ac = (const float*)d_in[9];
  const float* Ws1c  = (const float*)d_in[10];
  const float* b1c   = (const float*)d_in[11];
  const float* Wm2ca = (const float*)d_in[12];
  const float* Ws2a  = (const float*)d_in[13];
  const float* b2a   = (const float*)d_in[14];
  const float* Wm2ac = (const float*)d_in[15];
  const float* Ws2c  = (const float*)d_in[16];
  const float* b2c   = (const float*)d_in[17];
  const float* bng_c = (const float*)d_in[18];
  const float* bnb_c = (const float*)d_in[19];
  const float* bng_a = (const float*)d_in[20];
  const float* bnb_a = (const float*)d_in[21];
  const float* Wd1   = (const float*)d_in[22];
  const float* bd1   = (const float*)d_in[23];
  const float* Wd2   = (const float*)d_in[24];
  const float* bd2   = (const float*)d_in[25];
  float* out = (float*)d_out;

  // workspace carve (~430 MB)
  char* p = (char*)d_ws;
  auto alloc = [&](size_t bytes) -> char* {
    char* r = p; p += (bytes + 255) & ~(size_t)255; return r;
  };
  int* dega = (int*)alloc((size_t)NAN_ * 4);         // also reused as scatter cursor
  int* degc = (int*)alloc((size_t)NCN * 4);
  int* rpa  = (int*)alloc((size_t)(NAN_ + 1) * 4);
  int* rpc  = (int*)alloc((size_t)(NCN + 1) * 4);
  int* bsa  = (int*)alloc(512);
  int* bsc  = (int*)alloc(512);
  int* cola = (int*)alloc((size_t)NE * 4);
  int* colc = (int*)alloc((size_t)NE * 4);
  float* MA = (float*)alloc((size_t)NAN_ * DIM * 4); // mean_a -> U_a
  float* MC = (float*)alloc((size_t)NCN * DIM * 4);  // mean_c -> U_c
  float* HA = (float*)alloc((size_t)NAN_ * DIM * 4); // h_a -> z_a
  float* HC = (float*)alloc((size_t)NCN * DIM * 4);  // h_c -> z_c
  unsigned short* Wt    = (unsigned short*)alloc(8 * 16384 * 2);
  unsigned short* Wpt_c = (unsigned short*)alloc(16384 * 2);
  unsigned short* Wpt_a = (unsigned short*)alloc(16384 * 2);
  float* bnbuf = (float*)alloc(512 * 4);
  float* bfull = (float*)alloc(128 * 4);

  // --- CSR build (shared by both layers) ---
  (void)hipMemsetAsync(dega, 0, (size_t)NAN_ * 4, stream);
  (void)hipMemsetAsync(degc, 0, (size_t)NCN * 4, stream);
  k_count<<<(NE + 255) / 256, 256, 0, stream>>>(e_src, e_dst, dega, degc);

  int nba = (NAN_ + 4095) / 4096, nbc = (NCN + 4095) / 4096;
  k_scan1<<<nba, 256, 0, stream>>>(dega, rpa, bsa, NAN_);
  k_scanb<<<1, 128, 0, stream>>>(bsa, nba);
  k_scan3<<<(NAN_ + 256) / 256, 256, 0, stream>>>(rpa, bsa, NAN_, NE);
  k_scan1<<<nbc, 256, 0, stream>>>(degc, rpc, bsc, NCN);
  k_scanb<<<1, 128, 0, stream>>>(bsc, nbc);
  k_scan3<<<(NCN + 256) / 256, 256, 0, stream>>>(rpc, bsc, NCN, NE);

  (void)hipMemsetAsync(dega, 0, (size_t)NAN_ * 4, stream);
  (void)hipMemsetAsync(degc, 0, (size_t)NCN * 4, stream);
  k_scatter<<<(NE + 255) / 256, 256, 0, stream>>>(e_src, e_dst, rpa, rpc,
                                                  dega, degc, cola, colc);

  // --- transpose+cast the 8 encoder weights to bf16 [n][k] ---
  WtArgs wa;
  wa.s[0] = Wm1ca; wa.s[1] = Ws1a; wa.s[2] = Wm1ac; wa.s[3] = Ws1c;
  wa.s[4] = Wm2ca; wa.s[5] = Ws2a; wa.s[6] = Wm2ac; wa.s[7] = Ws2c;
  k_wtrans<<<8, 256, 0, stream>>>(wa, Wt);

  int agA = (NAN_ * 64 + 255) / 256, agC = (NCN * 64 + 255) / 256;
  int gba = (NAN_ + 127) / 128, gbc = (NCN + 127) / 128;

  // --- layer 1 ---
  k_agg<<<agA, 256, 0, stream>>>(x_c, rpa, cola, MA, NAN_);
  k_agg<<<agC, 256, 0, stream>>>(x_a, rpc, colc, MC, NCN);
  k_gemm<<<gba, 256, 0, stream>>>(MA, Wt + 0 * 16384, x_a, Wt + 1 * 16384, b1a, HA, NAN_, 1);
  k_gemm<<<gbc, 256, 0, stream>>>(MC, Wt + 2 * 16384, x_c, Wt + 3 * 16384, b1c, HC, NCN, 1);

  // --- layer 2 ---
  k_agg<<<agA, 256, 0, stream>>>(HC, rpa, cola, MA, NAN_);
  k_agg<<<agC, 256, 0, stream>>>(HA, rpc, colc, MC, NCN);
  k_gemm<<<gba, 256, 0, stream>>>(MA, Wt + 4 * 16384, HA, Wt + 5 * 16384, b2a, HA, NAN_, 0);
  k_gemm<<<gbc, 256, 0, stream>>>(MC, Wt + 6 * 16384, HC, Wt + 7 * 16384, b2c, HC, NCN, 0);

  // --- batch norm stats + fold into decoder weights ---
  (void)hipMemsetAsync(bnbuf, 0, 512 * 4, stream);
  k_bnstats<<<512, 256, 0, stream>>>(HA, NAN_, bnbuf + 0,   bnbuf + 128);
  k_bnstats<<<512, 256, 0, stream>>>(HC, NCN,  bnbuf + 256, bnbuf + 384);
  k_bnprep<<<1, 128, 0, stream>>>(bnbuf, bng_c, bnb_c, bng_a, bnb_a, Wd1, bd1,
                                  Wpt_c, Wpt_a, bfull);

  // --- decoder precompute U = zbn @ W_dec1_half (BN folded into Wpt/bfull) ---
  k_gemm<<<gba, 256, 0, stream>>>(HA, Wpt_a, nullptr, nullptr, nullptr, MA, NAN_, 0);
  k_gemm<<<gbc, 256, 0, stream>>>(HC, Wpt_c, nullptr, nullptr, nullptr, MC, NCN, 0);

  // --- per-edge decoder ---
  k_dec<<<4096, 256, 0, stream>>>(l_c, l_a, MC, MA, bfull, Wd2, bd2, out, NL);
}

// Round 2
// 1738.254 us; speedup vs baseline: 1.4546x; 1.4546x over previous
//
#include <hip/hip_runtime.h>
#include <hip/hip_bf16.h>

#define NCN 300000
#define NAN_ 100000
#define DIM 128
#define NE 2000000
#define NL 1000000

typedef __attribute__((ext_vector_type(8))) short bf16x8;
typedef __attribute__((ext_vector_type(4))) float f32x4;
typedef __attribute__((ext_vector_type(8))) unsigned short u16x8;
typedef __attribute__((ext_vector_type(4))) unsigned short u16x4;

static __device__ __forceinline__ unsigned short f2bf(float x){
  union { float f; unsigned u; } v; v.f = x;
  unsigned r = (v.u + 0x7FFFu + ((v.u >> 16) & 1u)) >> 16;
  return (unsigned short)r;
}
static __device__ __forceinline__ float bf2f(unsigned short h){
  union { unsigned u; float f; } v; v.u = ((unsigned)h) << 16; return v.f;
}

// ---------------- fp32 -> bf16 cast ----------------
__global__ void k_cast(const float* __restrict__ x, unsigned short* __restrict__ y, int n4){
  int i = blockIdx.x * blockDim.x + threadIdx.x;
  if (i < n4){
    float4 v = ((const float4*)x)[i];
    u16x4 h;
    h[0] = f2bf(v.x); h[1] = f2bf(v.y); h[2] = f2bf(v.z); h[3] = f2bf(v.w);
    ((u16x4*)y)[i] = h;
  }
}

// ---------------- CSR build ----------------
__global__ void k_count(const int* __restrict__ src, const int* __restrict__ dst,
                        int* dega, int* degc){
  int e = blockIdx.x * blockDim.x + threadIdx.x;
  if (e < NE){
    atomicAdd(&dega[dst[e]], 1);
    atomicAdd(&degc[src[e]], 1);
  }
}

__global__ void k_scan1(const int* __restrict__ in, int* __restrict__ out,
                        int* __restrict__ bsum, int n){
  int t = threadIdx.x;
  int base = blockIdx.x * 4096 + t * 16;
  int v[16];
  int tot = 0;
  #pragma unroll
  for (int i = 0; i < 16; i++){
    int x = (base + i < n) ? in[base + i] : 0;
    v[i] = tot; tot += x;
  }
  int lane = t & 63, w = t >> 6;
  int inc = tot;
  #pragma unroll
  for (int o = 1; o < 64; o <<= 1){ int u = __shfl_up(inc, o); if (lane >= o) inc += u; }
  __shared__ int ws[4];
  if (lane == 63) ws[w] = inc;
  __syncthreads();
  int woff = 0;
  for (int j = 0; j < w; j++) woff += ws[j];
  int ex = woff + inc - tot;
  #pragma unroll
  for (int i = 0; i < 16; i++) if (base + i < n) out[base + i] = ex + v[i];
  if (t == 255) bsum[blockIdx.x] = woff + inc;
}

__global__ void k_scanb(int* bs, int nb){
  int t = threadIdx.x;
  int vv = (t < nb) ? bs[t] : 0;
  int lane = t & 63, w = t >> 6;
  int inc = vv;
  #pragma unroll
  for (int o = 1; o < 64; o <<= 1){ int u = __shfl_up(inc, o); if (lane >= o) inc += u; }
  __shared__ int ws[2];
  if (lane == 63) ws[w] = inc;
  __syncthreads();
  int off = (w == 1) ? ws[0] : 0;
  if (t < nb) bs[t] = off + inc - vv;
}

__global__ void k_scan3(int* __restrict__ rp, const int* __restrict__ bs, int n, int total){
  int idx = blockIdx.x * blockDim.x + threadIdx.x;
  if (idx < n) rp[idx] += bs[idx >> 12];
  if (idx == 0) rp[n] = total;
}

__global__ void k_scatter(const int* __restrict__ src, const int* __restrict__ dst,
                          const int* __restrict__ rpa, const int* __restrict__ rpc,
                          int* cura, int* curc, int* cola, int* colc){
  int e = blockIdx.x * blockDim.x + threadIdx.x;
  if (e < NE){
    int s = src[e], d = dst[e];
    int pa = rpa[d] + atomicAdd(&cura[d], 1);
    cola[pa] = s;
    int pc = rpc[s] + atomicAdd(&curc[s], 1);
    colc[pc] = d;
  }
}

// ------- pull mean aggregation, bf16 in/out: one wave per dst, 4 edges in flight -------
__global__ void k_agg(const unsigned short* __restrict__ feat, const int* __restrict__ rp,
                      const int* __restrict__ col, unsigned short* __restrict__ outm, int ndst){
  int wid  = (blockIdx.x * blockDim.x + threadIdx.x) >> 6;
  int lane = threadIdx.x & 63;
  if (wid >= ndst) return;
  int g  = lane >> 4;        // edge subgroup 0..3
  int cl = lane & 15;        // 8-channel chunk index
  int beg = rp[wid], end = rp[wid + 1];
  float acc[8] = {0.f,0.f,0.f,0.f,0.f,0.f,0.f,0.f};
  for (int j = beg + g; j < end; j += 4){
    int s = col[j];
    u16x8 v = *(const u16x8*)(feat + (size_t)s * DIM + cl * 8);
    #pragma unroll
    for (int k = 0; k < 8; k++) acc[k] += bf2f(v[k]);
  }
  #pragma unroll
  for (int k = 0; k < 8; k++){
    acc[k] += __shfl_xor(acc[k], 16);
    acc[k] += __shfl_xor(acc[k], 32);
  }
  int d = end - beg;
  float inv = 1.0f / (float)(d > 1 ? d : 1);
  if (g == 0){
    u16x8 r;
    #pragma unroll
    for (int k = 0; k < 8; k++) r[k] = f2bf(acc[k] * inv);
    *(u16x8*)(outm + (size_t)wid * DIM + cl * 8) = r;
  }
}

// ------- bf16 MFMA GEMM: out[Mx128] = A@WA (+ B@WB) + bias, optional relu, bf16 out ----
// A/B are bf16 [row][128]; WtA/WtB bf16 TRANSPOSED [n][k]. In-place out==B safe
// (block stages its rows to LDS before storing; B rows used only by the same row range).
__global__ __launch_bounds__(256) void k_gemm(
    const unsigned short* __restrict__ A, const unsigned short* __restrict__ WtA,
    const unsigned short* __restrict__ B, const unsigned short* __restrict__ WtB,
    const float* __restrict__ bias, unsigned short* out, int M, int doRelu)
{
  __shared__ unsigned short lA[128 * 128];   // 32 KB, xor-swizzled 16B chunks
  __shared__ unsigned short lW[128 * 128];   // 32 KB
  int t = threadIdx.x;
  int lane = t & 63, wv = t >> 6;
  int row0 = blockIdx.x * 128;
  int m = lane & 15, kq = lane >> 4;

  f32x4 acc[2][8];
  #pragma unroll
  for (int i = 0; i < 2; i++)
    #pragma unroll
    for (int j = 0; j < 8; j++) acc[i][j] = (f32x4){0.f, 0.f, 0.f, 0.f};

  const unsigned short* src = A;
  const unsigned short* wt = WtA;
  for (int pass = 0; pass < 2; ++pass){
    if (pass == 1){
      if (!B) break;
      src = B; wt = WtB;
      __syncthreads();
    }
    // stage activation tile (bf16, 16B chunks, swizzle key = row&15)
    #pragma unroll
    for (int i = 0; i < 8; i++){
      int id = t + 256 * i;            // 0..2047 chunks
      int r = id >> 4, c = id & 15;
      int gr = row0 + r;
      u16x8 v = {0,0,0,0,0,0,0,0};
      if (gr < M) v = *(const u16x8*)(src + (size_t)gr * DIM + c * 8);
      int pc = c ^ (r & 15);
      *(u16x8*)&lA[r * 128 + pc * 8] = v;
    }
    // stage transposed weight swizzled
    #pragma unroll
    for (int i = 0; i < 8; i++){
      int id = t + 256 * i;
      int n = id >> 4, cc = id & 15;
      u16x8 w = *(const u16x8*)(wt + n * 128 + cc * 8);
      int pc = cc ^ (n & 15);
      *(u16x8*)&lW[n * 128 + pc * 8] = w;
    }
    __syncthreads();
    #pragma unroll
    for (int kc = 0; kc < 4; kc++){
      int cA = kc * 4 + kq;
      int r0 = wv * 32 + m;
      int r1 = r0 + 16;
      bf16x8 a0 = *(const bf16x8*)&lA[r0 * 128 + (cA ^ m) * 8];
      bf16x8 a1 = *(const bf16x8*)&lA[r1 * 128 + (cA ^ m) * 8];
      #pragma unroll
      for (int ct = 0; ct < 8; ct++){
        int n = ct * 16 + m;
        bf16x8 bfrag = *(const bf16x8*)&lW[n * 128 + (cA ^ m) * 8];
        acc[0][ct] = __builtin_amdgcn_mfma_f32_16x16x32_bf16(a0, bfrag, acc[0][ct], 0, 0, 0);
        acc[1][ct] = __builtin_amdgcn_mfma_f32_16x16x32_bf16(a1, bfrag, acc[1][ct], 0, 0, 0);
      }
    }
  }
  // epilogue: D col = lane&15, row = (lane>>4)*4 + reg   [verified m89/m91]
  #pragma unroll
  for (int rt = 0; rt < 2; rt++){
    int rbase = row0 + wv * 32 + rt * 16 + kq * 4;
    #pragma unroll
    for (int ct = 0; ct < 8; ct++){
      int colv = ct * 16 + m;
      float bv = bias ? bias[colv] : 0.f;
      #pragma unroll
      for (int r = 0; r < 4; r++){
        int grow = rbase + r;
        if (grow < M){
          float vo = acc[rt][ct][r] + bv;
          if (doRelu) vo = fmaxf(vo, 0.f);
          out[(size_t)grow * DIM + colv] = f2bf(vo);
        }
      }
    }
  }
}

// ---------------- weight transpose fp32 [k][n] -> bf16 [n][k], batched ----------------
struct WtArgs { const float* s[8]; };
__global__ void k_wtrans(WtArgs a, unsigned short* dstb){
  const float* W = a.s[blockIdx.x];
  unsigned short* Wt = dstb + blockIdx.x * 16384;
  int t = threadIdx.x;
  for (int i = 0; i < 64; i++){
    int id = t + 256 * i;
    int k = id >> 7, n = id & 127;
    Wt[n * 128 + k] = f2bf(W[id]);
  }
}

// ---------------- batch-norm column stats (bf16 input) ----------------
__global__ void k_bnstats(const unsigned short* __restrict__ z, int M, float* gsum, float* gsq){
  int ch = threadIdx.x & 127, half = threadIdx.x >> 7;
  float s = 0.f, q = 0.f;
  for (int r = blockIdx.x * 2 + half; r < M; r += gridDim.x * 2){
    float v = bf2f(z[(size_t)r * DIM + ch]);
    s += v; q += v * v;
  }
  __shared__ float ls[256], lq[256];
  ls[threadIdx.x] = s; lq[threadIdx.x] = q;
  __syncthreads();
  if (half == 0){
    atomicAdd(&gsum[ch], ls[ch] + ls[ch + 128]);
    atomicAdd(&gsq[ch],  lq[ch] + lq[ch + 128]);
  }
}

// bn finalize + fold BN into decoder weight halves; bfull = b_dec1 + t_c@Wc + t_a@Wa
__global__ void k_bnprep(const float* sums,   // [sum_a, sq_a, sum_c, sq_c] x128
                         const float* gc, const float* bc,
                         const float* ga, const float* ba,
                         const float* Wd1, const float* bd1,
                         unsigned short* Wpt_c, unsigned short* Wpt_a, float* bfull){
  int n = threadIdx.x;   // 128 threads
  __shared__ float sc[128], tc[128], sa[128], ta[128];
  {
    float mu = sums[256 + n] / (float)NCN;
    float var = sums[384 + n] / (float)NCN - mu * mu;
    float s = gc[n] * rsqrtf(var + 1e-5f);
    sc[n] = s; tc[n] = bc[n] - mu * s;
  }
  {
    float mu = sums[0 + n] / (float)NAN_;
    float var = sums[128 + n] / (float)NAN_ - mu * mu;
    float s = ga[n] * rsqrtf(var + 1e-5f);
    sa[n] = s; ta[n] = ba[n] - mu * s;
  }
  __syncthreads();
  float accv = bd1[n];
  for (int k = 0; k < 128; k++){
    float w1 = Wd1[k * DIM + n];
    float w2 = Wd1[(128 + k) * DIM + n];
    Wpt_c[n * 128 + k] = f2bf(sc[k] * w1);
    Wpt_a[n * 128 + k] = f2bf(sa[k] * w2);
    accv += tc[k] * w1 + ta[k] * w2;
  }
  bfull[n] = accv;
}

// ---------------- decoder: one half-wave per label edge (bf16 U) ----------------
__global__ void k_dec(const int* __restrict__ lc, const int* __restrict__ la,
                      const unsigned short* __restrict__ UC, const unsigned short* __restrict__ UA,
                      const float* __restrict__ bfull, const float* __restrict__ w2,
                      const float* __restrict__ b2, float* __restrict__ out, int Etot){
  int t  = blockIdx.x * blockDim.x + threadIdx.x;
  int sl = t & 31;
  int eid = t >> 5;
  int ne = (gridDim.x * blockDim.x) >> 5;
  f32x4 bb = *(const f32x4*)(bfull + sl * 4);
  f32x4 ww = *(const f32x4*)(w2 + sl * 4);
  float b2v = b2[0];
  for (int e = eid; e < Etot; e += ne){
    int ic = lc[e], ia = la[e];
    u16x4 uc = *(const u16x4*)(UC + (size_t)ic * DIM + sl * 4);
    u16x4 ua = *(const u16x4*)(UA + (size_t)ia * DIM + sl * 4);
    float d = 0.f;
    #pragma unroll
    for (int k = 0; k < 4; k++){
      float x = fmaxf(bf2f(uc[k]) + bf2f(ua[k]) + bb[k], 0.f);
      d += x * ww[k];
    }
    #pragma unroll
    for (int o = 16; o; o >>= 1) d += __shfl_xor(d, o);
    if (sl == 0) out[e] = d + b2v;
  }
}

extern "C" void kernel_launch(void* const* d_in, const int* in_sizes, int n_in,
                              void* d_out, int out_size, void* d_ws, size_t ws_size,
                              hipStream_t stream){
  const float* x_c  = (const float*)d_in[0];
  const float* x_a  = (const float*)d_in[1];
  const int* e_src  = (const int*)d_in[2];
  const int* e_dst  = (const int*)d_in[3];
  const int* l_c    = (const int*)d_in[4];
  const int* l_a    = (const int*)d_in[5];
  const float* Wm1ca = (const float*)d_in[6];
  const float* Ws1a  = (const float*)d_in[7];
  const float* b1a   = (const float*)d_in[8];
  const float* Wm1ac = (const float*)d_in[9];
  const float* Ws1c  = (const float*)d_in[10];
  const float* b1c   = (const float*)d_in[11];
  const float* Wm2ca = (const float*)d_in[12];
  const float* Ws2a  = (const float*)d_in[13];
  const float* b2a   = (const float*)d_in[14];
  const float* Wm2ac = (const float*)d_in[15];
  const float* Ws2c  = (const float*)d_in[16];
  const float* b2c   = (const float*)d_in[17];
  const float* bng_c = (const float*)d_in[18];
  const float* bnb_c = (const float*)d_in[19];
  const float* bng_a = (const float*)d_in[20];
  const float* bnb_a = (const float*)d_in[21];
  const float* Wd1   = (const float*)d_in[22];
  const float* bd1   = (const float*)d_in[23];
  const float* Wd2   = (const float*)d_in[24];
  const float* bd2   = (const float*)d_in[25];
  float* out = (float*)d_out;

  // workspace carve (~330 MB)
  char* p = (char*)d_ws;
  auto alloc = [&](size_t bytes) -> char* {
    char* r = p; p += (bytes + 255) & ~(size_t)255; return r;
  };
  int* dega = (int*)alloc((size_t)NAN_ * 4);         // also reused as scatter cursor
  int* degc = (int*)alloc((size_t)NCN * 4);
  int* rpa  = (int*)alloc((size_t)(NAN_ + 1) * 4);
  int* rpc  = (int*)alloc((size_t)(NCN + 1) * 4);
  int* bsa  = (int*)alloc(512);
  int* bsc  = (int*)alloc(512);
  int* cola = (int*)alloc((size_t)NE * 4);
  int* colc = (int*)alloc((size_t)NE * 4);
  unsigned short* XC = (unsigned short*)alloc((size_t)NCN * DIM * 2);   // bf16 x_customer
  unsigned short* XA = (unsigned short*)alloc((size_t)NAN_ * DIM * 2);  // bf16 x_article
  unsigned short* MA = (unsigned short*)alloc((size_t)NAN_ * DIM * 2);  // mean_a -> U_a
  unsigned short* MC = (unsigned short*)alloc((size_t)NCN * DIM * 2);   // mean_c -> U_c
  unsigned short* HA = (unsigned short*)alloc((size_t)NAN_ * DIM * 2);  // h_a -> z_a
  unsigned short* HC = (unsigned short*)alloc((size_t)NCN * DIM * 2);   // h_c -> z_c
  unsigned short* Wt    = (unsigned short*)alloc(8 * 16384 * 2);
  unsigned short* Wpt_c = (unsigned short*)alloc(16384 * 2);
  unsigned short* Wpt_a = (unsigned short*)alloc(16384 * 2);
  float* bnbuf = (float*)alloc(512 * 4);
  float* bfull = (float*)alloc(128 * 4);

  // --- bf16 pre-cast of node features ---
  k_cast<<<(NCN * DIM / 4 + 255) / 256, 256, 0, stream>>>(x_c, XC, NCN * DIM / 4);
  k_cast<<<(NAN_ * DIM / 4 + 255) / 256, 256, 0, stream>>>(x_a, XA, NAN_ * DIM / 4);

  // --- CSR build (shared by both layers) ---
  (void)hipMemsetAsync(dega, 0, (size_t)NAN_ * 4, stream);
  (void)hipMemsetAsync(degc, 0, (size_t)NCN * 4, stream);
  k_count<<<(NE + 255) / 256, 256, 0, stream>>>(e_src, e_dst, dega, degc);

  int nba = (NAN_ + 4095) / 4096, nbc = (NCN + 4095) / 4096;
  k_scan1<<<nba, 256, 0, stream>>>(dega, rpa, bsa, NAN_);
  k_scanb<<<1, 128, 0, stream>>>(bsa, nba);
  k_scan3<<<(NAN_ + 256) / 256, 256, 0, stream>>>(rpa, bsa, NAN_, NE);
  k_scan1<<<nbc, 256, 0, stream>>>(degc, rpc, bsc, NCN);
  k_scanb<<<1, 128, 0, stream>>>(bsc, nbc);
  k_scan3<<<(NCN + 256) / 256, 256, 0, stream>>>(rpc, bsc, NCN, NE);

  (void)hipMemsetAsync(dega, 0, (size_t)NAN_ * 4, stream);
  (void)hipMemsetAsync(degc, 0, (size_t)NCN * 4, stream);
  k_scatter<<<(NE + 255) / 256, 256, 0, stream>>>(e_src, e_dst, rpa, rpc,
                                                  dega, degc, cola, colc);

  // --- transpose+cast the 8 encoder weights to bf16 [n][k] ---
  WtArgs wa;
  wa.s[0] = Wm1ca; wa.s[1] = Ws1a; wa.s[2] = Wm1ac; wa.s[3] = Ws1c;
  wa.s[4] = Wm2ca; wa.s[5] = Ws2a; wa.s[6] = Wm2ac; wa.s[7] = Ws2c;
  k_wtrans<<<8, 256, 0, stream>>>(wa, Wt);

  int agA = (NAN_ * 64 + 255) / 256, agC = (NCN * 64 + 255) / 256;
  int gba = (NAN_ + 127) / 128, gbc = (NCN + 127) / 128;

  // --- layer 1 ---
  k_agg<<<agA, 256, 0, stream>>>(XC, rpa, cola, MA, NAN_);
  k_agg<<<agC, 256, 0, stream>>>(XA, rpc, colc, MC, NCN);
  k_gemm<<<gba, 256, 0, stream>>>(MA, Wt + 0 * 16384, XA, Wt + 1 * 16384, b1a, HA, NAN_, 1);
  k_gemm<<<gbc, 256, 0, stream>>>(MC, Wt + 2 * 16384, XC, Wt + 3 * 16384, b1c, HC, NCN, 1);

  // --- layer 2 ---
  k_agg<<<agA, 256, 0, stream>>>(HC, rpa, cola, MA, NAN_);
  k_agg<<<agC, 256, 0, stream>>>(HA, rpc, colc, MC, NCN);
  k_gemm<<<gba, 256, 0, stream>>>(MA, Wt + 4 * 16384, HA, Wt + 5 * 16384, b2a, HA, NAN_, 0);
  k_gemm<<<gbc, 256, 0, stream>>>(MC, Wt + 6 * 16384, HC, Wt + 7 * 16384, b2c, HC, NCN, 0);

  // --- batch norm stats + fold into decoder weights ---
  (void)hipMemsetAsync(bnbuf, 0, 512 * 4, stream);
  k_bnstats<<<512, 256, 0, stream>>>(HA, NAN_, bnbuf + 0,   bnbuf + 128);
  k_bnstats<<<512, 256, 0, stream>>>(HC, NCN,  bnbuf + 256, bnbuf + 384);
  k_bnprep<<<1, 128, 0, stream>>>(bnbuf, bng_c, bnb_c, bng_a, bnb_a, Wd1, bd1,
                                  Wpt_c, Wpt_a, bfull);

  // --- decoder precompute U = zbn @ W_dec1_half (BN folded into Wpt/bfull) ---
  k_gemm<<<gba, 256, 0, stream>>>(HA, Wpt_a, nullptr, nullptr, nullptr, MA, NAN_, 0);
  k_gemm<<<gbc, 256, 0, stream>>>(HC, Wpt_c, nullptr, nullptr, nullptr, MC, NCN, 0);

  // --- per-edge decoder ---
  k_dec<<<4096, 256, 0, stream>>>(l_c, l_a, MC, MA, bfull, Wd2, bd2, out, NL);
}

// Round 3
// 1380.294 us; speedup vs baseline: 1.8319x; 1.2593x over previous
//
#include <hip/hip_runtime.h>
#include <hip/hip_bf16.h>

#define NCN 300000
#define NAN_ 100000
#define DIM 128
#define NE 2000000
#define NL 1000000
#define NBA 1563          // ceil(NAN_/64)
#define NBC 4688          // ceil(NCN/64)
#define ECH 8192          // edges per binning block
#define NCHUNK ((NE + ECH - 1) / ECH)

typedef __attribute__((ext_vector_type(8))) short bf16x8;
typedef __attribute__((ext_vector_type(4))) float f32x4;
typedef __attribute__((ext_vector_type(8))) unsigned short u16x8;
typedef __attribute__((ext_vector_type(4))) unsigned short u16x4;

static __device__ __forceinline__ unsigned short f2bf(float x){
  union { float f; unsigned u; } v; v.f = x;
  unsigned r = (v.u + 0x7FFFu + ((v.u >> 16) & 1u)) >> 16;
  return (unsigned short)r;
}
static __device__ __forceinline__ float bf2f(unsigned short h){
  union { unsigned u; float f; } v; v.u = ((unsigned)h) << 16; return v.f;
}

// ---------------- fp32 -> bf16 cast ----------------
__global__ void k_cast(const float* __restrict__ x, unsigned short* __restrict__ y, int n4){
  int i = blockIdx.x * blockDim.x + threadIdx.x;
  if (i < n4){
    float4 v = ((const float4*)x)[i];
    u16x4 h;
    h[0] = f2bf(v.x); h[1] = f2bf(v.y); h[2] = f2bf(v.z); h[3] = f2bf(v.w);
    ((u16x4*)y)[i] = h;
  }
}

// ---------- pass 0: per-block LDS histogram of 64-wide dst buckets, both dirs ----------
__global__ void k_bcnt(const int* __restrict__ src, const int* __restrict__ dst,
                       int* cntA, int* cntC){
  __shared__ int h[NBA + NBC];
  int t = threadIdx.x;
  for (int i = t; i < NBA + NBC; i += 256) h[i] = 0;
  __syncthreads();
  int e0 = blockIdx.x * ECH;
  int e1 = e0 + ECH < NE ? e0 + ECH : NE;
  for (int e = e0 + t; e < e1; e += 256){
    int s = src[e], d = dst[e];
    atomicAdd(&h[d >> 6], 1);
    atomicAdd(&h[NBA + (s >> 6)], 1);
  }
  __syncthreads();
  for (int i = t; i < NBA + NBC; i += 256){
    int c = h[i];
    if (c > 0){
      if (i < NBA) atomicAdd(&cntA[i], c);
      else         atomicAdd(&cntC[i - NBA], c);
    }
  }
}

// ---------- scan bucket counts (block 0: A, block 1: C); writes base (excl) + cur copy ----
__global__ void k_scan2(const int* cA, int* bA, int* uA,
                        const int* cC, int* bC, int* uC){
  const int* c; int* bs; int* cu; int n;
  if (blockIdx.x == 0){ c = cA; bs = bA; cu = uA; n = NBA; }
  else                { c = cC; bs = bC; cu = uC; n = NBC; }
  int t = threadIdx.x;
  int per = (n + 255) / 256;          // <= 19
  int b0 = t * per;
  int vals[19];
  int s = 0;
  for (int i = 0; i < per; i++){
    int idx = b0 + i;
    int x = (idx < n) ? c[idx] : 0;
    vals[i] = s; s += x;
  }
  int lane = t & 63, w = t >> 6;
  int inc = s;
  #pragma unroll
  for (int o = 1; o < 64; o <<= 1){ int u = __shfl_up(inc, o); if (lane >= o) inc += u; }
  __shared__ int ws[4];
  if (lane == 63) ws[w] = inc;
  __syncthreads();
  int woff = 0;
  for (int j = 0; j < w; j++) woff += ws[j];
  int ex = woff + inc - s;
  for (int i = 0; i < per; i++){
    int idx = b0 + i;
    if (idx < n){ int v = ex + vals[i]; bs[idx] = v; cu[idx] = v; }
  }
  if (t == 255) bs[n] = ex + s;       // == NE
}

// ---------- pass 1: partition edges into (dst,src) pairs per bucket, both dirs ----------
__global__ void k_bin(const int* __restrict__ src, const int* __restrict__ dst,
                      int* curA, int* curC, int2* binA, int2* binC){
  __shared__ int h[NBA + NBC];
  int t = threadIdx.x;
  for (int i = t; i < NBA + NBC; i += 256) h[i] = 0;
  __syncthreads();
  int e0 = blockIdx.x * ECH;
  int e1 = e0 + ECH < NE ? e0 + ECH : NE;
  for (int e = e0 + t; e < e1; e += 256){
    int s = src[e], d = dst[e];
    atomicAdd(&h[d >> 6], 1);
    atomicAdd(&h[NBA + (s >> 6)], 1);
  }
  __syncthreads();
  for (int i = t; i < NBA + NBC; i += 256){
    int c = h[i];
    if (c > 0){
      int base = (i < NBA) ? atomicAdd(&curA[i], c) : atomicAdd(&curC[i - NBA], c);
      h[i] = base;
    }
  }
  __syncthreads();
  for (int e = e0 + t; e < e1; e += 256){
    int s = src[e], d = dst[e];
    int pa = atomicAdd(&h[d >> 6], 1);
    binA[pa] = make_int2(d, s);
    int pc = atomicAdd(&h[NBA + (s >> 6)], 1);
    binC[pc] = make_int2(s, d);
  }
}

// ---------- pass 2: per-bucket CSR finalize — emits rp and contiguous col ----------
__global__ void k_csr(const int2* __restrict__ bin, const int* __restrict__ base,
                      int* __restrict__ rp, int* __restrict__ col, int ndst, int nb){
  int b = blockIdx.x;
  int d0 = b << 6;
  int beg = base[b], end = base[b + 1];
  __shared__ int deg[64], cur[64];
  int t = threadIdx.x;
  if (t < 64) deg[t] = 0;
  __syncthreads();
  for (int i = beg + t; i < end; i += 256){
    int2 p = bin[i];
    atomicAdd(&deg[p.x - d0], 1);
  }
  __syncthreads();
  if (t < 64){
    int v = deg[t];
    int inc = v;
    #pragma unroll
    for (int o = 1; o < 64; o <<= 1){ int u = __shfl_up(inc, o); if (t >= o) inc += u; }
    int ex = beg + inc - v;
    cur[t] = ex;
    if (d0 + t < ndst) rp[d0 + t] = ex;
    if (b == nb - 1 && t == 0) rp[ndst] = base[nb];
  }
  __syncthreads();
  for (int i = beg + t; i < end; i += 256){
    int2 p = bin[i];
    int pos = atomicAdd(&cur[p.x - d0], 1);
    col[pos] = p.y;
  }
}

// ------- merged pull mean aggregation (both node types), bf16, 8 gathers in flight -------
__global__ void k_agg2(const unsigned short* __restrict__ fA, const int* __restrict__ rpA,
                       const int* __restrict__ colA, unsigned short* __restrict__ oA,
                       const unsigned short* __restrict__ fC, const int* __restrict__ rpC,
                       const int* __restrict__ colC, unsigned short* __restrict__ oC){
  int wid  = (blockIdx.x * blockDim.x + threadIdx.x) >> 6;
  int lane = threadIdx.x & 63;
  const unsigned short* feat; const int* rp; const int* col; unsigned short* outm; int d;
  if (wid < NAN_){ feat = fA; rp = rpA; col = colA; outm = oA; d = wid; }
  else if (wid < NAN_ + NCN){ feat = fC; rp = rpC; col = colC; outm = oC; d = wid - NAN_; }
  else return;
  int g  = lane >> 4;        // edge subgroup 0..3
  int cl = lane & 15;        // 8-channel chunk
  int beg = rp[d], end = rp[d + 1];
  float a0[8] = {0,0,0,0,0,0,0,0}, a1[8] = {0,0,0,0,0,0,0,0};
  int j = beg + g;
  for (; j + 4 < end; j += 8){
    int s0 = col[j], s1 = col[j + 4];
    u16x8 v0 = *(const u16x8*)(feat + (size_t)s0 * DIM + cl * 8);
    u16x8 v1 = *(const u16x8*)(feat + (size_t)s1 * DIM + cl * 8);
    #pragma unroll
    for (int k = 0; k < 8; k++){ a0[k] += bf2f(v0[k]); a1[k] += bf2f(v1[k]); }
  }
  if (j < end){
    int s0 = col[j];
    u16x8 v0 = *(const u16x8*)(feat + (size_t)s0 * DIM + cl * 8);
    #pragma unroll
    for (int k = 0; k < 8; k++) a0[k] += bf2f(v0[k]);
  }
  #pragma unroll
  for (int k = 0; k < 8; k++){
    float a = a0[k] + a1[k];
    a += __shfl_xor(a, 16);
    a += __shfl_xor(a, 32);
    a0[k] = a;
  }
  int dg = end - beg;
  float inv = 1.0f / (float)(dg > 1 ? dg : 1);
  if (g == 0){
    u16x8 r;
    #pragma unroll
    for (int k = 0; k < 8; k++) r[k] = f2bf(a0[k] * inv);
    *(u16x8*)(outm + (size_t)d * DIM + cl * 8) = r;
  }
}

// ------- bf16 MFMA GEMM: out[Mx128] = A@WA (+ B@WB) + bias, opt relu, opt BN stats ------
__global__ __launch_bounds__(256) void k_gemm(
    const unsigned short* __restrict__ A, const unsigned short* __restrict__ WtA,
    const unsigned short* __restrict__ B, const unsigned short* __restrict__ WtB,
    const float* __restrict__ bias, unsigned short* out, int M, int doRelu,
    float* gsum, float* gsq)
{
  __shared__ unsigned short lA[128 * 128];   // 32 KB, xor-swizzled 16B chunks
  __shared__ unsigned short lW[128 * 128];   // 32 KB
  int t = threadIdx.x;
  int lane = t & 63, wv = t >> 6;
  int row0 = blockIdx.x * 128;
  int m = lane & 15, kq = lane >> 4;

  f32x4 acc[2][8];
  #pragma unroll
  for (int i = 0; i < 2; i++)
    #pragma unroll
    for (int j = 0; j < 8; j++) acc[i][j] = (f32x4){0.f, 0.f, 0.f, 0.f};

  const unsigned short* src = A;
  const unsigned short* wt = WtA;
  for (int pass = 0; pass < 2; ++pass){
    if (pass == 1){
      if (!B) break;
      src = B; wt = WtB;
      __syncthreads();
    }
    #pragma unroll
    for (int i = 0; i < 8; i++){
      int id = t + 256 * i;
      int r = id >> 4, c = id & 15;
      int gr = row0 + r;
      u16x8 v = {0,0,0,0,0,0,0,0};
      if (gr < M) v = *(const u16x8*)(src + (size_t)gr * DIM + c * 8);
      int pc = c ^ (r & 15);
      *(u16x8*)&lA[r * 128 + pc * 8] = v;
    }
    #pragma unroll
    for (int i = 0; i < 8; i++){
      int id = t + 256 * i;
      int n = id >> 4, cc = id & 15;
      u16x8 w = *(const u16x8*)(wt + n * 128 + cc * 8);
      int pc = cc ^ (n & 15);
      *(u16x8*)&lW[n * 128 + pc * 8] = w;
    }
    __syncthreads();
    #pragma unroll
    for (int kc = 0; kc < 4; kc++){
      int cA = kc * 4 + kq;
      int r0 = wv * 32 + m;
      int r1 = r0 + 16;
      bf16x8 a0 = *(const bf16x8*)&lA[r0 * 128 + (cA ^ m) * 8];
      bf16x8 a1 = *(const bf16x8*)&lA[r1 * 128 + (cA ^ m) * 8];
      #pragma unroll
      for (int ct = 0; ct < 8; ct++){
        int n = ct * 16 + m;
        bf16x8 bfrag = *(const bf16x8*)&lW[n * 128 + (cA ^ m) * 8];
        acc[0][ct] = __builtin_amdgcn_mfma_f32_16x16x32_bf16(a0, bfrag, acc[0][ct], 0, 0, 0);
        acc[1][ct] = __builtin_amdgcn_mfma_f32_16x16x32_bf16(a1, bfrag, acc[1][ct], 0, 0, 0);
      }
    }
  }
  // epilogue: D col = lane&15, row = (lane>>4)*4 + reg   [verified m89/m91]
  float* lsum = (float*)lA;   // LDS reuse after barrier
  float* lsq  = lsum + 128;
  if (gsum){
    __syncthreads();
    if (t < 128){ lsum[t] = 0.f; lsq[t] = 0.f; }
    __syncthreads();
  }
  #pragma unroll
  for (int ct = 0; ct < 8; ct++){
    int colv = ct * 16 + m;
    float bv = bias ? bias[colv] : 0.f;
    float ps = 0.f, pq = 0.f;
    #pragma unroll
    for (int rt = 0; rt < 2; rt++){
      int rbase = row0 + wv * 32 + rt * 16 + kq * 4;
      #pragma unroll
      for (int r = 0; r < 4; r++){
        int grow = rbase + r;
        if (grow < M){
          float vo = acc[rt][ct][r] + bv;
          if (doRelu) vo = fmaxf(vo, 0.f);
          out[(size_t)grow * DIM + colv] = f2bf(vo);
          ps += vo; pq += vo * vo;
        }
      }
    }
    if (gsum){
      atomicAdd(&lsum[colv], ps);
      atomicAdd(&lsq[colv], pq);
    }
  }
  if (gsum){
    __syncthreads();
    if (t < 128){
      atomicAdd(&gsum[t], lsum[t]);
      atomicAdd(&gsq[t],  lsq[t]);
    }
  }
}

// ---------------- weight transpose fp32 [k][n] -> bf16 [n][k], batched ----------------
struct WtArgs { const float* s[8]; };
__global__ void k_wtrans(WtArgs a, unsigned short* dstb){
  const float* W = a.s[blockIdx.x];
  unsigned short* Wt = dstb + blockIdx.x * 16384;
  int t = threadIdx.x;
  for (int i = 0; i < 64; i++){
    int id = t + 256 * i;
    int k = id >> 7, n = id & 127;
    Wt[n * 128 + k] = f2bf(W[id]);
  }
}

// bn finalize + fold BN into decoder weight halves; bfull = b_dec1 + t_c@Wc + t_a@Wa
__global__ void k_bnprep(const float* sums,   // [sum_a, sq_a, sum_c, sq_c] x128
                         const float* gc, const float* bc,
                         const float* ga, const float* ba,
                         const float* Wd1, const float* bd1,
                         unsigned short* Wpt_c, unsigned short* Wpt_a, float* bfull){
  int n = threadIdx.x;   // 128 threads
  __shared__ float sc[128], tc[128], sa[128], ta[128];
  {
    float mu = sums[256 + n] / (float)NCN;
    float var = sums[384 + n] / (float)NCN - mu * mu;
    float s = gc[n] * rsqrtf(var + 1e-5f);
    sc[n] = s; tc[n] = bc[n] - mu * s;
  }
  {
    float mu = sums[0 + n] / (float)NAN_;
    float var = sums[128 + n] / (float)NAN_ - mu * mu;
    float s = ga[n] * rsqrtf(var + 1e-5f);
    sa[n] = s; ta[n] = ba[n] - mu * s;
  }
  __syncthreads();
  float accv = bd1[n];
  for (int k = 0; k < 128; k++){
    float w1 = Wd1[k * DIM + n];
    float w2 = Wd1[(128 + k) * DIM + n];
    Wpt_c[n * 128 + k] = f2bf(sc[k] * w1);
    Wpt_a[n * 128 + k] = f2bf(sa[k] * w2);
    accv += tc[k] * w1 + ta[k] * w2;
  }
  bfull[n] = accv;
}

// ---------------- decoder: half-wave per edge, 2 edges in flight ----------------
__global__ void k_dec(const int* __restrict__ lc, const int* __restrict__ la,
                      const unsigned short* __restrict__ UC, const unsigned short* __restrict__ UA,
                      const float* __restrict__ bfull, const float* __restrict__ w2,
                      const float* __restrict__ b2, float* __restrict__ out, int Etot){
  int t   = blockIdx.x * blockDim.x + threadIdx.x;
  int sl  = t & 31;
  int hw  = t >> 5;
  int nhw = (gridDim.x * blockDim.x) >> 5;
  f32x4 bb = *(const f32x4*)(bfull + sl * 4);
  f32x4 ww = *(const f32x4*)(w2 + sl * 4);
  float b2v = b2[0];
  for (int e0 = hw * 2; e0 < Etot; e0 += nhw * 2){
    int e1 = e0 + 1;                  // Etot even -> always valid
    int ic0 = lc[e0], ia0 = la[e0];
    int ic1 = lc[e1], ia1 = la[e1];
    u16x4 uc0 = *(const u16x4*)(UC + (size_t)ic0 * DIM + sl * 4);
    u16x4 ua0 = *(const u16x4*)(UA + (size_t)ia0 * DIM + sl * 4);
    u16x4 uc1 = *(const u16x4*)(UC + (size_t)ic1 * DIM + sl * 4);
    u16x4 ua1 = *(const u16x4*)(UA + (size_t)ia1 * DIM + sl * 4);
    float d0 = 0.f, d1 = 0.f;
    #pragma unroll
    for (int k = 0; k < 4; k++){
      float x0 = fmaxf(bf2f(uc0[k]) + bf2f(ua0[k]) + bb[k], 0.f);
      float x1 = fmaxf(bf2f(uc1[k]) + bf2f(ua1[k]) + bb[k], 0.f);
      d0 += x0 * ww[k];
      d1 += x1 * ww[k];
    }
    #pragma unroll
    for (int o = 16; o; o >>= 1){ d0 += __shfl_xor(d0, o); d1 += __shfl_xor(d1, o); }
    if (sl == 0){ out[e0] = d0 + b2v; out[e1] = d1 + b2v; }
  }
}

extern "C" void kernel_launch(void* const* d_in, const int* in_sizes, int n_in,
                              void* d_out, int out_size, void* d_ws, size_t ws_size,
                              hipStream_t stream){
  const float* x_c  = (const float*)d_in[0];
  const float* x_a  = (const float*)d_in[1];
  const int* e_src  = (const int*)d_in[2];
  const int* e_dst  = (const int*)d_in[3];
  const int* l_c    = (const int*)d_in[4];
  const int* l_a    = (const int*)d_in[5];
  const float* Wm1ca = (const float*)d_in[6];
  const float* Ws1a  = (const float*)d_in[7];
  const float* b1a   = (const float*)d_in[8];
  const float* Wm1ac = (const float*)d_in[9];
  const float* Ws1c  = (const float*)d_in[10];
  const float* b1c   = (const float*)d_in[11];
  const float* Wm2ca = (const float*)d_in[12];
  const float* Ws2a  = (const float*)d_in[13];
  const float* b2a   = (const float*)d_in[14];
  const float* Wm2ac = (const float*)d_in[15];
  const float* Ws2c  = (const float*)d_in[16];
  const float* b2c   = (const float*)d_in[17];
  const float* bng_c = (const float*)d_in[18];
  const float* bnb_c = (const float*)d_in[19];
  const float* bng_a = (const float*)d_in[20];
  const float* bnb_a = (const float*)d_in[21];
  const float* Wd1   = (const float*)d_in[22];
  const float* bd1   = (const float*)d_in[23];
  const float* Wd2   = (const float*)d_in[24];
  const float* bd2   = (const float*)d_in[25];
  float* out = (float*)d_out;

  // workspace carve
  char* p = (char*)d_ws;
  auto alloc = [&](size_t bytes) -> char* {
    char* r = p; p += (bytes + 255) & ~(size_t)255; return r;
  };
  int* cnt   = (int*)alloc((size_t)(NBA + NBC) * 4);  // cntA | cntC contiguous
  int* cntA  = cnt;
  int* cntC  = cnt + NBA;
  int* baseA = (int*)alloc((size_t)(NBA + 1) * 4);
  int* baseC = (int*)alloc((size_t)(NBC + 1) * 4);
  int* curA  = (int*)alloc((size_t)NBA * 4);
  int* curC  = (int*)alloc((size_t)NBC * 4);
  int2* binA = (int2*)alloc((size_t)NE * 8);
  int2* binC = (int2*)alloc((size_t)NE * 8);
  int* rpa   = (int*)alloc((size_t)(NAN_ + 1) * 4);
  int* rpc   = (int*)alloc((size_t)(NCN + 1) * 4);
  int* cola  = (int*)alloc((size_t)NE * 4);
  int* colc  = (int*)alloc((size_t)NE * 4);
  unsigned short* XC = (unsigned short*)alloc((size_t)NCN * DIM * 2);
  unsigned short* XA = (unsigned short*)alloc((size_t)NAN_ * DIM * 2);
  unsigned short* MA = (unsigned short*)alloc((size_t)NAN_ * DIM * 2);  // mean_a -> U_a
  unsigned short* MC = (unsigned short*)alloc((size_t)NCN * DIM * 2);   // mean_c -> U_c
  unsigned short* HA = (unsigned short*)alloc((size_t)NAN_ * DIM * 2);  // h_a -> z_a
  unsigned short* HC = (unsigned short*)alloc((size_t)NCN * DIM * 2);   // h_c -> z_c
  unsigned short* Wt    = (unsigned short*)alloc(8 * 16384 * 2);
  unsigned short* Wpt_c = (unsigned short*)alloc(16384 * 2);
  unsigned short* Wpt_a = (unsigned short*)alloc(16384 * 2);
  float* bnbuf = (float*)alloc(512 * 4);
  float* bfull = (float*)alloc(128 * 4);

  // --- bf16 pre-cast of node features ---
  k_cast<<<(NCN * DIM / 4 + 255) / 256, 256, 0, stream>>>(x_c, XC, NCN * DIM / 4);
  k_cast<<<(NAN_ * DIM / 4 + 255) / 256, 256, 0, stream>>>(x_a, XA, NAN_ * DIM / 4);

  // --- CSR build via 64-wide destination buckets ---
  (void)hipMemsetAsync(cnt, 0, (size_t)(NBA + NBC) * 4, stream);
  k_bcnt<<<NCHUNK, 256, 0, stream>>>(e_src, e_dst, cntA, cntC);
  k_scan2<<<2, 256, 0, stream>>>(cntA, baseA, curA, cntC, baseC, curC);
  k_bin<<<NCHUNK, 256, 0, stream>>>(e_src, e_dst, curA, curC, binA, binC);
  k_csr<<<NBA, 256, 0, stream>>>(binA, baseA, rpa, cola, NAN_, NBA);
  k_csr<<<NBC, 256, 0, stream>>>(binC, baseC, rpc, colc, NCN, NBC);

  // --- transpose+cast the 8 encoder weights to bf16 [n][k] ---
  WtArgs wa;
  wa.s[0] = Wm1ca; wa.s[1] = Ws1a; wa.s[2] = Wm1ac; wa.s[3] = Ws1c;
  wa.s[4] = Wm2ca; wa.s[5] = Ws2a; wa.s[6] = Wm2ac; wa.s[7] = Ws2c;
  k_wtrans<<<8, 256, 0, stream>>>(wa, Wt);

  int agg_blocks = ((NAN_ + NCN) * 64 + 255) / 256;
  int gba = (NAN_ + 127) / 128, gbc = (NCN + 127) / 128;

  (void)hipMemsetAsync(bnbuf, 0, 512 * 4, stream);

  // --- layer 1 ---
  k_agg2<<<agg_blocks, 256, 0, stream>>>(XC, rpa, cola, MA, XA, rpc, colc, MC);
  k_gemm<<<gba, 256, 0, stream>>>(MA, Wt + 0 * 16384, XA, Wt + 1 * 16384, b1a, HA, NAN_, 1, nullptr, nullptr);
  k_gemm<<<gbc, 256, 0, stream>>>(MC, Wt + 2 * 16384, XC, Wt + 3 * 16384, b1c, HC, NCN, 1, nullptr, nullptr);

  // --- layer 2 (BN column stats fused into epilogue) ---
  k_agg2<<<agg_blocks, 256, 0, stream>>>(HC, rpa, cola, MA, HA, rpc, colc, MC);
  k_gemm<<<gba, 256, 0, stream>>>(MA, Wt + 4 * 16384, HA, Wt + 5 * 16384, b2a, HA, NAN_, 0, bnbuf + 0,   bnbuf + 128);
  k_gemm<<<gbc, 256, 0, stream>>>(MC, Wt + 6 * 16384, HC, Wt + 7 * 16384, b2c, HC, NCN, 0, bnbuf + 256, bnbuf + 384);

  // --- BN finalize folded into decoder weights ---
  k_bnprep<<<1, 128, 0, stream>>>(bnbuf, bng_c, bnb_c, bng_a, bnb_a, Wd1, bd1,
                                  Wpt_c, Wpt_a, bfull);

  // --- decoder precompute U = zbn @ W_dec1_half (BN folded into Wpt/bfull) ---
  k_gemm<<<gba, 256, 0, stream>>>(HA, Wpt_a, nullptr, nullptr, nullptr, MA, NAN_, 0, nullptr, nullptr);
  k_gemm<<<gbc, 256, 0, stream>>>(HC, Wpt_c, nullptr, nullptr, nullptr, MC, NCN, 0, nullptr, nullptr);

  // --- per-edge decoder ---
  k_dec<<<4096, 256, 0, stream>>>(l_c, l_a, MC, MA, bfull, Wd2, bd2, out, NL);
}